// Round 11
// baseline (183.014 us; speedup 1.0000x reference)
//
#include <hip/hip_runtime.h>
#include <stdint.h>

#define N_ANCH 36864
#define KCAND  4096
#define NBUCK  384
#define NSEL   300
#define NGT    64
#define NBATCH 16
#define SCORE_THRESH 0.908f
// conservative uncertain-band threshold: dt <= 0.75 here => dt*2^-23 <= 9e-8 << 4e-7
#define BAND (-4e-7f)

typedef unsigned long long u64;

__device__ __forceinline__ float clip01(float v) { return fminf(fmaxf(v, 0.0f), 1.0f); }

// ---- Exact division-free suppression, single-accumulator form ----
// Reference decision: RN(inter / D) >= 0.5, D = ((aa+ab) - inter) + 1e-7f.
// dd = RN(inter - 0.5*D) via fma (0.5*D exact, fma rounds once -> == inter-dt).
// Sign-exact (Sterbenz / big-gap / x-x=+0):
//   dd >= 0               -> q >= 0.5 certainly
//   dd <  -dt*2^-23       -> q <  0.5 certainly
//   dd in [-dt*2^-23, 0)  -> uncertain 1-ulp band -> exact division rerun.
// m = max(dd): m >= 0 <=> exists certain-suppress; rerun iff m in [BAND, 0)
// (conservative superset; false rerun just re-divides exactly).
// Duplicate tests are idempotent under max.
__device__ __forceinline__ void supp_acc(const float4 A, float Aa, const float4 B, float ab,
                                         float& m) {
    float y1 = fmaxf(A.x, B.x);
    float x1 = fmaxf(A.y, B.y);
    float y2 = fminf(A.z, B.z);
    float x2 = fminf(A.w, B.w);
    float ih = fmaxf(y2 - y1, 0.0f);
    float iw = fmaxf(x2 - x1, 0.0f);
    float inter = ih * iw;
    float D  = ((Aa + ab) - inter) + 1e-7f;   // exact reference op order
    m = fmaxf(m, fmaf(-0.5f, D, inter));      // == RN(inter - dt), sign-exact
}

__device__ __forceinline__ bool supp_div(const float4 A, float Aa, const float4 B, float ab) {
    float y1 = fmaxf(A.x, B.x);
    float x1 = fmaxf(A.y, B.y);
    float y2 = fminf(A.z, B.z);
    float x2 = fminf(A.w, B.w);
    float ih = fmaxf(y2 - y1, 0.0f);
    float iw = fmaxf(x2 - x1, 0.0f);
    float inter = ih * iw;
    float D = ((Aa + ab) - inter) + 1e-7f;
    return (inter / D) >= 0.5f;               // exact IEEE decision
}

// single test: certain flag + uncertain flag (for intra-chunk bit masks)
__device__ __forceinline__ void supp_bit(const float4 A, float Aa, const float4 B, float ab,
                                         bool& sj, bool& uj) {
    float y1 = fmaxf(A.x, B.x);
    float x1 = fmaxf(A.y, B.y);
    float y2 = fminf(A.z, B.z);
    float x2 = fminf(A.w, B.w);
    float ih = fmaxf(y2 - y1, 0.0f);
    float iw = fmaxf(x2 - x1, 0.0f);
    float inter = ih * iw;
    float D  = ((Aa + ab) - inter) + 1e-7f;
    float dd = fmaf(-0.5f, D, inter);
    sj = dd >= 0.0f;
    uj = (dd >= BAND) && !sj;
}

__device__ __forceinline__ float4 decode_one(const float4 a4, const float4 d4) {
    float ah = a4.z - a4.x, aw = a4.w - a4.y;
    float acy = a4.x + 0.5f * ah, acx = a4.y + 0.5f * aw;
    float h = expf(d4.z) * ah, w = expf(d4.w) * aw;
    float cy = d4.x * ah + acy, cx = d4.y * aw + acx;
    float y1 = cy - 0.5f * h, x1 = cx - 0.5f * w;
    return make_float4(y1, x1, y1 + h, x1 + w);
}

// scores in (0.908, 1.0) all share exponent 0x7E -> ulp-linear bucket digit,
// ascending digit == descending score. width 4096 ulps -> lambda ~9 per bucket.
__device__ __forceinline__ int bucket_of(float s) {
    unsigned d = (0x3F800000u - __float_as_uint(s)) >> 12;
    return (d < NBUCK) ? (int)d : (NBUCK - 1);
}

// ---- wave-0 serial resolve of one 128-pair, WITH folded catch-up ----
// Catch-up: both halves vs accepts [cuLo, accLow) (the accepts added by the
// previous pair's resolve, which this pair's long loop did not see).
// Then: resolve half1 -> cross-test half2 vs half1's new accepts -> resolve
// half2.  All candidate data held in registers (2 candidates per lane).
__device__ __forceinline__ void resolve_pair(
    int lane, int C1p, int C2p,
    const unsigned* pre, const unsigned* gmlo, const unsigned* gmhi,
    const float4* cbox, const float* carea,
    float4* accB, float* accA, int cuLo, int accLow, int* accCountPtr)
{
    float4 c0p = make_float4(0.f,0.f,0.f,0.f), c1p = make_float4(0.f,0.f,0.f,0.f);
    float a0p = 0.f, a1p = 0.f;
    if (lane < C1p) { c0p = cbox[lane];      a0p = carea[lane]; }
    if (lane < C2p) { c1p = cbox[64 + lane]; a1p = carea[64 + lane]; }

    // catch-up (lane-parallel, uniform loop over ~12 new accepts)
    float mc0 = -1.f, mc1 = -1.f;
    for (int a = cuLo; a < accLow; ++a) {
        float4 A = accB[a]; float Aa = accA[a];
        supp_acc(A, Aa, c0p, a0p, mc0);
        supp_acc(A, Aa, c1p, a1p, mc1);
    }
    bool cu0 = (mc0 >= 0.f), cu1 = (mc1 >= 0.f);
    bool rrc = ((mc0 < 0.f) && (mc0 >= BAND)) || ((mc1 < 0.f) && (mc1 >= BAND));
    if (__builtin_expect(__any((int)rrc), 0)) {
        for (int a = cuLo; a < accLow; ++a) {
            float4 A = accB[a]; float Aa = accA[a];
            cu0 |= supp_div(A, Aa, c0p, a0p);
            cu1 |= supp_div(A, Aa, c1p, a1p);
        }
    }

    // resolve half1
    u64 mymask = ((u64)gmhi[lane] << 32) | (u64)gmlo[lane];
    bool alive = (lane < C1p) && (pre[lane] == 0u) && !cu0;
    u64 accbits = 0ull, done = 0ull;
    int room = NSEL - accLow;
    int na = 0;
    while (na < room) {
        u64 am  = __ballot(alive);
        u64 rem = am & ~done;
        if (!rem) break;
        int l = __ffsll(rem) - 1;
        done = (2ull << l) - 1ull;
        accbits |= (1ull << l);
        ++na;
        if ((mymask >> l) & 1ull) alive = false;
    }
    if ((accbits >> lane) & 1ull) {
        int rank = __popcll(accbits & ((1ull << lane) - 1ull));
        accB[accLow + rank] = c0p;
        accA[accLow + rank] = a0p;
    }
    int acc1 = accLow + __popcll(accbits);

    // cross: half2 vs half1's new accepts
    float m1b = -1.f;
    for (int a3 = accLow; a3 < acc1; ++a3)
        supp_acc(accB[a3], accA[a3], c1p, a1p, m1b);
    bool cross = (m1b >= 0.f);
    bool rr2 = (m1b < 0.f) && (m1b >= BAND);
    if (__builtin_expect(__any((int)rr2), 0)) {
        for (int a3 = accLow; a3 < acc1; ++a3)
            cross |= supp_div(accB[a3], accA[a3], c1p, a1p);
    }

    // resolve half2
    u64 mymask2 = ((u64)gmhi[64 + lane] << 32) | (u64)gmlo[64 + lane];
    bool alive2 = (lane < C2p) && (pre[64 + lane] == 0u) && !cu1 && !cross;
    u64 accbits2 = 0ull; done = 0ull;
    int room2 = NSEL - acc1;
    na = 0;
    while (na < room2) {
        u64 am  = __ballot(alive2);
        u64 rem = am & ~done;
        if (!rem) break;
        int l = __ffsll(rem) - 1;
        done = (2ull << l) - 1ull;
        accbits2 |= (1ull << l);
        ++na;
        if ((mymask2 >> l) & 1ull) alive2 = false;
    }
    if ((accbits2 >> lane) & 1ull) {
        int rank = __popcll(accbits2 & ((1ull << lane) - 1ull));
        accB[acc1 + rank] = c1p;
        accA[acc1 + rank] = a1p;
    }
    if (lane == 0) *accCountPtr = acc1 + __popcll(accbits2);
}

__global__ __launch_bounds__(1024)
void roi_bbox_kernel(const float* __restrict__ deltas,
                     const float* __restrict__ labels,
                     const float* __restrict__ anchors,
                     const float* __restrict__ gt,
                     float* __restrict__ out)
{
    __shared__ u64    s_sorted[KCAND];   // 32 KB, bucket-ordered then rank-sorted
    __shared__ int    s_hist[NBUCK];
    __shared__ int    s_cur[NBUCK];
    __shared__ int    s_base[NBUCK + 1];
    __shared__ float4 s_accB[NSEL + 4];  // accepted raw (unclipped) boxes, pop order
    __shared__ float  s_accA[NSEL + 4];  // accepted areas (written once at accept)
    __shared__ float4 s_cbox[3][128];    // TRIPLE-buffered pair boxes (mod-3 pipeline)
    __shared__ float  s_carea[3][128];   // their areas
    __shared__ unsigned int s_pre[3][128];   // suppression flags per candidate
    __shared__ unsigned int s_gmlo[3][128];  // intra-half 64-bit masks (lo)
    __shared__ unsigned int s_gmhi[3][128];  // intra-half 64-bit masks (hi)
    __shared__ int   s_accCount;
    __shared__ float s_merged[NSEL];
    __shared__ int   s_gtbest[NSEL];
    __shared__ float4 s_gt[NGT];
    __shared__ int   s_selidx[64];

    const int b    = blockIdx.x;
    const int tid  = threadIdx.x;
    const int lane = tid & 63;
    const int wv   = tid >> 6;
    const float*  sc    = labels + (size_t)b * N_ANCH;
    const float4* sc4   = (const float4*)sc;
    const float4* anch4 = (const float4*)(anchors + (size_t)b * N_ANCH * 4);
    const float4* del4  = (const float4*)(deltas  + (size_t)b * N_ANCH * 4);
    const float4* gt4   = (const float4*)(gt + (size_t)b * NGT * 4);

    if (tid < NBUCK) s_hist[tid] = 0;
    if (tid == 0) s_accCount = 0;
    __syncthreads();

    // ---- Phase A1: bucket histogram (float4-vectorized) ----
    for (int i = tid; i < N_ANCH / 4; i += 1024) {
        float4 v = sc4[i];
        float vv[4] = {v.x, v.y, v.z, v.w};
        #pragma unroll
        for (int k = 0; k < 4; ++k)
            if (vv[k] > SCORE_THRESH) atomicAdd(&s_hist[bucket_of(vv[k])], 1);
    }
    __syncthreads();

    // ---- exclusive scan of 384 counts (wave 0: 6 counts/lane + shfl scan) ----
    if (tid < 64) {
        int c[6]; int sum = 0;
        #pragma unroll
        for (int k = 0; k < 6; ++k) { c[k] = s_hist[tid * 6 + k]; sum += c[k]; }
        int inc = sum;
        #pragma unroll
        for (int off = 1; off < 64; off <<= 1) {
            int v = __shfl_up(inc, off);
            if (lane >= off) inc += v;
        }
        int excl = inc - sum;
        #pragma unroll
        for (int k = 0; k < 6; ++k) {
            s_base[tid * 6 + k] = excl;
            s_cur[tid * 6 + k]  = excl;
            excl += c[k];
        }
        if (tid == 63) s_base[NBUCK] = excl;
    }
    __syncthreads();

    // ---- Phase A2: scatter keys into bucket regions (L2-hot reload, vectorized) ----
    for (int i = tid; i < N_ANCH / 4; i += 1024) {
        float4 v = sc4[i];
        float vv[4] = {v.x, v.y, v.z, v.w};
        #pragma unroll
        for (int k = 0; k < 4; ++k) {
            float sval = vv[k];
            if (sval > SCORE_THRESH) {
                int idx = i * 4 + k;
                int pos = atomicAdd(&s_cur[bucket_of(sval)], 1);
                if (pos < KCAND)
                    s_sorted[pos] = ((u64)__float_as_uint(sval) << 32)
                                  | (u64)(0xFFFFFFFFu - (unsigned)idx);
            }
        }
    }
    __syncthreads();

    // ---- per-bucket rank sort (one wave per bucket, no barriers inside) ----
    for (int bk = wv; bk < NBUCK; bk += 16) {
        int lo = s_base[bk], hi = s_base[bk + 1];
        if (lo > KCAND) lo = KCAND;
        if (hi > KCAND) hi = KCAND;
        int n = hi - lo;
        if (n <= 1) continue;
        u64 mykey = (lane < n) ? s_sorted[lo + lane] : 0ull;
        int rank = 0;
        for (int j = 0; j < n; ++j) {          // broadcast reads, conflict-free
            u64 kj = s_sorted[lo + j];
            rank += (kj > mykey);
        }
        if (lane < n) s_sorted[lo + rank] = mykey;  // in-wave: reads precede write
    }
    __syncthreads();

    int M = s_base[NBUCK]; if (M > KCAND) M = KCAND;

    // ---- pre-loop: decode pair 0 into buffer 0, zero buffer-0 masks ----
    if (tid < 128) {
        s_pre[0][tid] = 0u; s_gmlo[0][tid] = 0u; s_gmhi[0][tid] = 0u;
        if (tid < M) {
            u64 key = s_sorted[tid];
            int idx = (int)(0xFFFFFFFFu - (unsigned)(key & 0xFFFFFFFFull));
            float4 bx = decode_one(anch4[idx], del4[idx]);
            s_cbox[0][tid]  = bx;
            s_carea[0][tid] = (bx.z - bx.x) * (bx.w - bx.y);
        }
    }
    __syncthreads();

    // ---- Phase B: SINGLE-BARRIER pipelined NMS, 128-candidate pairs ----
    // Iteration k (buffers mod 3: bk=k%3 test, bn=(k+1)%3 decode, bp=(k+2)%3
    // == (k-1)%3 resolve):
    //   wv0: resolve pair k-1 (catch-up [acc(k-3),acc(k-2)) folded in);
    //   wv1: zero + decode pair k+1;
    //   wv2..15: long-loop pair k vs accepted [0, acc(k-2)) (14 slices)
    //            + intra masks (wv2..8 half1, wv9..15 half2; 7 slices each).
    //   ONE __syncthreads per pair.
    // Coverage per candidate: [0,k-2] long-loop, [k-2,k-1) catch-up (at its
    // own resolve), own-pair half1 via cross, own-half via bit masks
    // -> identical sequential-NMS semantics (proven structure, R9 + R8).
    int accLLprev = 0;   // accepted through pair k-3
    int accLL     = 0;   // accepted through pair k-2 (long-loop bound)
    int k = 0, start = 0;
    for (; start < M && accLL < NSEL; start += 128, ++k) {
        int bk = k % 3;
        int bn = (k + 1) % 3;
        int bp = (k + 2) % 3;                  // == (k-1)%3
        int C  = M - start; if (C > 128) C = 128;
        int C1 = C < 64 ? C : 64;
        int C2 = C - C1;
        int c  = lane;

        if (wv == 0) {
            if (k > 0) {
                int startp = start - 128;
                int Cp = M - startp; if (Cp > 128) Cp = 128;
                int C1p = Cp < 64 ? Cp : 64;
                int C2p = Cp - C1p;
                resolve_pair(lane, C1p, C2p,
                             s_pre[bp], s_gmlo[bp], s_gmhi[bp],
                             s_cbox[bp], s_carea[bp],
                             s_accB, s_accA, accLLprev, accLL, &s_accCount);
            }
        } else if (wv == 1) {
            // zero next pair's masks, then decode it (buffer of pair k-2,
            // whose resolve completed last iteration -> barrier-separated)
            s_pre[bn][c]       = 0u; s_pre[bn][64+c]  = 0u;
            s_gmlo[bn][c]      = 0u; s_gmlo[bn][64+c] = 0u;
            s_gmhi[bn][c]      = 0u; s_gmhi[bn][64+c] = 0u;
            int ni0 = start + 128 + c;
            int ni1 = start + 192 + c;
            if (ni0 < M) {
                u64 key = s_sorted[ni0];
                int idx = (int)(0xFFFFFFFFu - (unsigned)(key & 0xFFFFFFFFull));
                float4 bx = decode_one(anch4[idx], del4[idx]);
                s_cbox[bn][c]  = bx;
                s_carea[bn][c] = (bx.z - bx.x) * (bx.w - bx.y);
            }
            if (ni1 < M) {
                u64 key = s_sorted[ni1];
                int idx = (int)(0xFFFFFFFFu - (unsigned)(key & 0xFFFFFFFFull));
                float4 bx = decode_one(anch4[idx], del4[idx]);
                s_cbox[bn][64+c]  = bx;
                s_carea[bn][64+c] = (bx.z - bx.x) * (bx.w - bx.y);
            }
        } else {
            // test waves 2..15: long-loop vs accepted [0, accLL), 14 slices
            int sidx = wv - 2;                 // 0..13
            float4 c0 = make_float4(0.f,0.f,0.f,0.f), c1 = make_float4(0.f,0.f,0.f,0.f);
            float a0 = 0.f, a1 = 0.f;
            if (c < C1) { c0 = s_cbox[bk][c];      a0 = s_carea[bk][c]; }
            if (c < C2) { c1 = s_cbox[bk][64+c];   a1 = s_carea[bk][64+c]; }

            float m0 = -1.f, m1 = -1.f;
            int a = sidx;
            for (; a + 14 < accLL; a += 28) {
                float4 A0 = s_accB[a];
                float4 A1 = s_accB[a + 14];
                float Aa0 = s_accA[a];
                float Aa1 = s_accA[a + 14];
                supp_acc(A0, Aa0, c0, a0, m0);
                supp_acc(A0, Aa0, c1, a1, m1);
                supp_acc(A1, Aa1, c0, a0, m0);
                supp_acc(A1, Aa1, c1, a1, m1);
            }
            if (a < accLL) {
                float4 A0 = s_accB[a];
                float Aa0 = s_accA[a];
                supp_acc(A0, Aa0, c0, a0, m0);
                supp_acc(A0, Aa0, c1, a1, m1);
            }
            bool s0 = (m0 >= 0.f), s1 = (m1 >= 0.f);
            bool rr = ((m0 < 0.f) && (m0 >= BAND)) || ((m1 < 0.f) && (m1 >= BAND));
            if (__builtin_expect(__any((int)rr), 0)) {
                for (int a2 = sidx; a2 < accLL; a2 += 14) {
                    float4 A = s_accB[a2];
                    float Aa = s_accA[a2];
                    s0 |= supp_div(A, Aa, c0, a0);
                    s1 |= supp_div(A, Aa, c1, a1);
                }
            }
            if (s0 && c < C1) s_pre[bk][c]      = 1u;   // same-value race, benign
            if (s1 && c < C2) s_pre[bk][64 + c] = 1u;

            if (wv <= 8) {
                // intra half1: waves 2..8, 7 slices
                int s7 = wv - 2;
                if (c < C1) {
                    unsigned mlo = 0u, mhi = 0u;
                    bool ur = false;
                    for (int j = s7; j < c; j += 7) {
                        float4 bj = s_cbox[bk][j];
                        float  aj = s_carea[bk][j];
                        bool sj, uj;
                        supp_bit(bj, aj, c0, a0, sj, uj);
                        ur |= uj;
                        unsigned bit = sj ? 1u : 0u;
                        if (j < 32) mlo |= bit << j; else mhi |= bit << (j - 32);
                    }
                    if (__builtin_expect(__any((int)ur), 0)) {
                        for (int j = s7; j < c; j += 7) {
                            float4 bj = s_cbox[bk][j];
                            float  aj = s_carea[bk][j];
                            unsigned bit = supp_div(bj, aj, c0, a0) ? 1u : 0u;
                            if (j < 32) mlo |= bit << j; else mhi |= bit << (j - 32);
                        }
                    }
                    if (mlo) atomicOr(&s_gmlo[bk][c], mlo);
                    if (mhi) atomicOr(&s_gmhi[bk][c], mhi);
                }
            } else {
                // intra half2: waves 9..15, 7 slices
                int s7 = wv - 9;
                if (c < C2) {
                    unsigned mlo = 0u, mhi = 0u;
                    bool ur = false;
                    for (int jj = s7; jj < c; jj += 7) {
                        float4 bj = s_cbox[bk][64 + jj];
                        float  aj = s_carea[bk][64 + jj];
                        bool sj, uj;
                        supp_bit(bj, aj, c1, a1, sj, uj);
                        ur |= uj;
                        unsigned bit = sj ? 1u : 0u;
                        if (jj < 32) mlo |= bit << jj; else mhi |= bit << (jj - 32);
                    }
                    if (__builtin_expect(__any((int)ur), 0)) {
                        for (int jj = s7; jj < c; jj += 7) {
                            float4 bj = s_cbox[bk][64 + jj];
                            float  aj = s_carea[bk][64 + jj];
                            unsigned bit = supp_div(bj, aj, c1, a1) ? 1u : 0u;
                            if (jj < 32) mlo |= bit << jj; else mhi |= bit << (jj - 32);
                        }
                    }
                    if (mlo) atomicOr(&s_gmlo[bk][64 + c], mlo);
                    if (mhi) atomicOr(&s_gmhi[bk][64 + c], mhi);
                }
            }
        }
        __syncthreads();
        accLLprev = accLL;
        accLL = s_accCount;                    // accepted through pair k-1
    }

    // ---- epilogue: resolve the final tested pair (pair k-1) ----
    if (k > 0) {
        if (wv == 0) {
            int startp = start - 128;
            int Cp = M - startp; if (Cp > 128) Cp = 128;
            if (Cp < 0) Cp = 0;
            int C1p = Cp < 64 ? Cp : 64;
            int C2p = Cp - C1p;
            int bp = (k + 2) % 3;              // (k-1)%3
            resolve_pair(lane, C1p, C2p,
                         s_pre[bp], s_gmlo[bp], s_gmhi[bp],
                         s_cbox[bp], s_carea[bp],
                         s_accB, s_accA, accLLprev, accLL, &s_accCount);
        }
        __syncthreads();
    }
    int accCount = s_accCount;
    if (accCount > NSEL) accCount = NSEL;

    // ---- Phase C: select_rois ----
    if (tid < NGT) s_gt[tid] = gt4[tid];
    __syncthreads();

    if (tid < NSEL) {
        float4 bx;
        if (tid < accCount) {
            float4 r = s_accB[tid];
            bx = make_float4(clip01(r.x), clip01(r.y), clip01(r.z), clip01(r.w));
        } else bx = make_float4(0.f, 0.f, 0.f, 0.f);
        float aa = (bx.z - bx.x) * (bx.w - bx.y);
        float best = -1e38f; int bi = 0;
        for (int g = 0; g < NGT; ++g) {
            float4 gb = s_gt[g];
            float y1 = fmaxf(bx.x, gb.x);
            float x1 = fmaxf(bx.y, gb.y);
            float y2 = fminf(bx.z, gb.z);
            float x2 = fminf(bx.w, gb.w);
            float ih = fmaxf(y2 - y1, 0.0f);
            float iw = fmaxf(x2 - x1, 0.0f);
            float inter = ih * iw;
            float ab = (gb.z - gb.x) * (gb.w - gb.y);
            float iou = inter / (aa + ab - inter + 1e-7f);
            if (iou > best) { best = iou; bi = g; }   // first-occurrence argmax
        }
        s_merged[tid] = best;
        s_gtbest[tid] = bi;
    }
    __syncthreads();

    // stable top-64 via rank selection: rank = #{j: v_j > v_i || (v_j==v_i && j<i)}
    if (tid < NSEL) {
        float v = s_merged[tid];
        int rank = 0;
        for (int j = 0; j < NSEL; ++j) {
            float u = s_merged[j];
            rank += (u > v) || (u == v && j < tid);
        }
        if (rank < 64) s_selidx[rank] = tid;
    }
    __syncthreads();

    // ---- outputs ----
    float* outIdx = out + (size_t)NBATCH * 128 * 4;   // 8192 box floats first
    if (tid < 256) {
        int r = tid >> 2, cc = tid & 3;
        int i = s_selidx[r];
        float val = 0.0f;
        if (i < accCount) {
            const float* p = (const float*)&s_accB[i];
            val = clip01(p[cc]);
        }
        out[((size_t)b * 128 + r) * 4 + cc] = val;
    } else if (tid < 512) {
        int j = tid - 256;
        out[((size_t)b * 128 + 64) * 4 + j] = 0.0f;   // TOTAL_NEG zero boxes
    } else if (tid < 576) {
        int r = tid - 512;
        outIdx[b * 64 + r] = (float)s_gtbest[s_selidx[r]];
    }
}

extern "C" void kernel_launch(void* const* d_in, const int* in_sizes, int n_in,
                              void* d_out, int out_size, void* d_ws, size_t ws_size,
                              hipStream_t stream) {
    const float* deltas  = (const float*)d_in[0];
    const float* labels  = (const float*)d_in[1];
    const float* anchors = (const float*)d_in[2];
    const float* gt      = (const float*)d_in[3];
    float* out = (float*)d_out;
    roi_bbox_kernel<<<NBATCH, 1024, 0, stream>>>(deltas, labels, anchors, gt, out);
}

// Round 13
// 156.118 us; speedup vs baseline: 1.1723x; 1.1723x over previous
//
#include <hip/hip_runtime.h>
#include <stdint.h>

#define N_ANCH 36864
#define KCAND  4096
#define NBUCK  384
#define NSEL   300
#define NGT    64
#define NBATCH 16
#define SCORE_THRESH 0.908f
// conservative uncertain-band threshold: dt <= 0.75 here => dt*2^-23 <= 9e-8 << 4e-7
#define BAND (-4e-7f)

typedef unsigned long long u64;

__device__ __forceinline__ float clip01(float v) { return fminf(fmaxf(v, 0.0f), 1.0f); }

// ---- Exact division-free suppression, single-accumulator form ----
// Reference decision: RN(inter / D) >= 0.5, D = ((aa+ab) - inter) + 1e-7f.
// dd = RN(inter - 0.5*D) via fma (0.5*D exact, fma rounds once -> == inter-dt).
// Sign-exact (Sterbenz / big-gap / x-x=+0):
//   dd >= 0               -> q >= 0.5 certainly
//   dd <  -dt*2^-23       -> q <  0.5 certainly
//   dd in [-dt*2^-23, 0)  -> uncertain 1-ulp band -> exact division rerun.
// m = max(dd): m >= 0 <=> exists certain-suppress; rerun iff m in [BAND, 0)
// (conservative superset; false rerun just re-divides exactly).
// Duplicate tests are idempotent under max.
__device__ __forceinline__ void supp_acc(const float4 A, float Aa, const float4 B, float ab,
                                         float& m) {
    float y1 = fmaxf(A.x, B.x);
    float x1 = fmaxf(A.y, B.y);
    float y2 = fminf(A.z, B.z);
    float x2 = fminf(A.w, B.w);
    float ih = fmaxf(y2 - y1, 0.0f);
    float iw = fmaxf(x2 - x1, 0.0f);
    float inter = ih * iw;
    float D  = ((Aa + ab) - inter) + 1e-7f;   // exact reference op order
    m = fmaxf(m, fmaf(-0.5f, D, inter));      // == RN(inter - dt), sign-exact
}

__device__ __forceinline__ bool supp_div(const float4 A, float Aa, const float4 B, float ab) {
    float y1 = fmaxf(A.x, B.x);
    float x1 = fmaxf(A.y, B.y);
    float y2 = fminf(A.z, B.z);
    float x2 = fminf(A.w, B.w);
    float ih = fmaxf(y2 - y1, 0.0f);
    float iw = fmaxf(x2 - x1, 0.0f);
    float inter = ih * iw;
    float D = ((Aa + ab) - inter) + 1e-7f;
    return (inter / D) >= 0.5f;               // exact IEEE decision
}

// single test: certain flag + uncertain flag (for intra-chunk bit masks)
__device__ __forceinline__ void supp_bit(const float4 A, float Aa, const float4 B, float ab,
                                         bool& sj, bool& uj) {
    float y1 = fmaxf(A.x, B.x);
    float x1 = fmaxf(A.y, B.y);
    float y2 = fminf(A.z, B.z);
    float x2 = fminf(A.w, B.w);
    float ih = fmaxf(y2 - y1, 0.0f);
    float iw = fmaxf(x2 - x1, 0.0f);
    float inter = ih * iw;
    float D  = ((Aa + ab) - inter) + 1e-7f;
    float dd = fmaf(-0.5f, D, inter);
    sj = dd >= 0.0f;
    uj = (dd >= BAND) && !sj;
}

__device__ __forceinline__ float4 decode_one(const float4 a4, const float4 d4) {
    float ah = a4.z - a4.x, aw = a4.w - a4.y;
    float acy = a4.x + 0.5f * ah, acx = a4.y + 0.5f * aw;
    float h = expf(d4.z) * ah, w = expf(d4.w) * aw;
    float cy = d4.x * ah + acy, cx = d4.y * aw + acx;
    float y1 = cy - 0.5f * h, x1 = cx - 0.5f * w;
    return make_float4(y1, x1, y1 + h, x1 + w);
}

__device__ __forceinline__ float area_of(const float4 b) {
    return (b.z - b.x) * (b.w - b.y);
}

// scores in (0.908, 1.0) all share exponent 0x7E -> ulp-linear bucket digit,
// ascending digit == descending score. width 4096 ulps -> lambda ~9 per bucket.
__device__ __forceinline__ int bucket_of(float s) {
    unsigned d = (0x3F800000u - __float_as_uint(s)) >> 12;
    return (d < NBUCK) ? (int)d : (NBUCK - 1);
}

__global__ __launch_bounds__(1024)
void roi_bbox_kernel(const float* __restrict__ deltas,
                     const float* __restrict__ labels,
                     const float* __restrict__ anchors,
                     const float* __restrict__ gt,
                     float* __restrict__ out)
{
    __shared__ u64    s_sorted[KCAND];   // 32 KB, bucket-ordered then rank-sorted
    __shared__ int    s_hist[NBUCK];
    __shared__ int    s_cur[NBUCK];
    __shared__ int    s_base[NBUCK + 1];
    __shared__ float4 s_accB[NSEL + 4];  // accepted raw (unclipped) boxes, pop order
    __shared__ float4 s_cbox[2][128];    // double-buffered PAIR boxes (128/pair)
    __shared__ unsigned int s_pre[2][128];   // suppression flags per candidate
    __shared__ unsigned int s_gmlo[2][128];  // intra-half 64-bit masks (lo)
    __shared__ unsigned int s_gmhi[2][128];  // intra-half 64-bit masks (hi)
    __shared__ int   s_accCount;
    __shared__ float s_merged[NSEL];
    __shared__ int   s_gtbest[NSEL];
    __shared__ float4 s_gt[NGT];
    __shared__ int   s_selidx[64];

    const int b    = blockIdx.x;
    const int tid  = threadIdx.x;
    const int lane = tid & 63;
    const int wv   = tid >> 6;
    const float*  sc    = labels + (size_t)b * N_ANCH;
    const float4* sc4   = (const float4*)sc;
    const float4* anch4 = (const float4*)(anchors + (size_t)b * N_ANCH * 4);
    const float4* del4  = (const float4*)(deltas  + (size_t)b * N_ANCH * 4);
    const float4* gt4   = (const float4*)(gt + (size_t)b * NGT * 4);

    if (tid < NBUCK) s_hist[tid] = 0;
    if (tid == 0) s_accCount = 0;
    __syncthreads();

    // ---- Phase A1: bucket histogram (float4-vectorized) ----
    for (int i = tid; i < N_ANCH / 4; i += 1024) {
        float4 v = sc4[i];
        float vv[4] = {v.x, v.y, v.z, v.w};
        #pragma unroll
        for (int k = 0; k < 4; ++k)
            if (vv[k] > SCORE_THRESH) atomicAdd(&s_hist[bucket_of(vv[k])], 1);
    }
    __syncthreads();

    // ---- exclusive scan of 384 counts (wave 0: 6 counts/lane + shfl scan) ----
    if (tid < 64) {
        int c[6]; int sum = 0;
        #pragma unroll
        for (int k = 0; k < 6; ++k) { c[k] = s_hist[tid * 6 + k]; sum += c[k]; }
        int inc = sum;
        #pragma unroll
        for (int off = 1; off < 64; off <<= 1) {
            int v = __shfl_up(inc, off);
            if (lane >= off) inc += v;
        }
        int excl = inc - sum;
        #pragma unroll
        for (int k = 0; k < 6; ++k) {
            s_base[tid * 6 + k] = excl;
            s_cur[tid * 6 + k]  = excl;
            excl += c[k];
        }
        if (tid == 63) s_base[NBUCK] = excl;
    }
    __syncthreads();

    // ---- Phase A2: scatter keys into bucket regions (L2-hot reload, vectorized) ----
    for (int i = tid; i < N_ANCH / 4; i += 1024) {
        float4 v = sc4[i];
        float vv[4] = {v.x, v.y, v.z, v.w};
        #pragma unroll
        for (int k = 0; k < 4; ++k) {
            float sval = vv[k];
            if (sval > SCORE_THRESH) {
                int idx = i * 4 + k;
                int pos = atomicAdd(&s_cur[bucket_of(sval)], 1);
                if (pos < KCAND)
                    s_sorted[pos] = ((u64)__float_as_uint(sval) << 32)
                                  | (u64)(0xFFFFFFFFu - (unsigned)idx);
            }
        }
    }
    __syncthreads();

    // ---- per-bucket rank sort (one wave per bucket, no barriers inside) ----
    for (int bk = wv; bk < NBUCK; bk += 16) {
        int lo = s_base[bk], hi = s_base[bk + 1];
        if (lo > KCAND) lo = KCAND;
        if (hi > KCAND) hi = KCAND;
        int n = hi - lo;
        if (n <= 1) continue;
        u64 mykey = (lane < n) ? s_sorted[lo + lane] : 0ull;
        int rank = 0;
        for (int j = 0; j < n; ++j) {          // broadcast reads, conflict-free
            u64 kj = s_sorted[lo + j];
            rank += (kj > mykey);
        }
        if (lane < n) s_sorted[lo + rank] = mykey;  // in-wave: reads precede write
    }
    __syncthreads();

    int M = s_base[NBUCK]; if (M > KCAND) M = KCAND;

    // ---- pre-loop: decode pair 0 (128 candidates), zero parity-0 masks ----
    if (tid < 128) {
        s_pre[0][tid] = 0u; s_gmlo[0][tid] = 0u; s_gmhi[0][tid] = 0u;
        if (tid < M) {
            u64 key = s_sorted[tid];
            int idx = (int)(0xFFFFFFFFu - (unsigned)(key & 0xFFFFFFFFull));
            s_cbox[0][tid] = decode_one(anch4[idx], del4[idx]);
        }
    }
    __syncthreads();

    // ---- Phase B: greedy NMS, 128-candidate pairs (R8 region structure) ----
    // R1: wv1 decode/zero next; waves{0,2..15} long-loop both halves (branchless,
    //     unroll x2); waves 2..9 intra-half1.   bar
    // R2: wave0 resolve half1 || waves 9..15 intra-half2.   bar
    // R3: half2 vs new accepts (15 slices).   bar
    // R4: wave0 resolve half2.   bar
    // Areas are RECOMPUTED in VALU (3 instr) everywhere; no area arrays in LDS.
    int accCount = 0;
    for (int start = 0; start < M && accCount < NSEL; start += 128) {
        int p  = (start >> 7) & 1;
        int C  = M - start; if (C > 128) C = 128;
        int C1 = C < 64 ? C : 64;
        int C2 = C - C1;                       // candidates in half2 (0..64)
        int c  = lane;
        int sidx15 = (wv == 0) ? 0 : (wv - 1); // 15-slice id for waves {0,2..15}

        float4 c0 = make_float4(0.f,0.f,0.f,0.f), c1 = make_float4(0.f,0.f,0.f,0.f);
        float a0 = 0.f, a1 = 0.f;

        // ---------------- Region 1 ----------------
        if (wv == 1) {
            s_pre[p^1][c]       = 0u; s_pre[p^1][64+c]  = 0u;
            s_gmlo[p^1][c]      = 0u; s_gmlo[p^1][64+c] = 0u;
            s_gmhi[p^1][c]      = 0u; s_gmhi[p^1][64+c] = 0u;
            int ni0 = start + 128 + c;
            int ni1 = start + 192 + c;
            if (ni0 < M) {
                u64 key = s_sorted[ni0];
                int idx = (int)(0xFFFFFFFFu - (unsigned)(key & 0xFFFFFFFFull));
                s_cbox[p^1][c] = decode_one(anch4[idx], del4[idx]);
            }
            if (ni1 < M) {
                u64 key = s_sorted[ni1];
                int idx = (int)(0xFFFFFFFFu - (unsigned)(key & 0xFFFFFFFFull));
                s_cbox[p^1][64+c] = decode_one(anch4[idx], del4[idx]);
            }
        } else {
            // candidate registers (zero-box for invalid lanes: inter==0 always,
            // never suppressed, never triggers the uncertain band)
            if (c < C1) c0 = s_cbox[p][c];
            if (c < C2) c1 = s_cbox[p][64+c];
            a0 = area_of(c0);
            a1 = area_of(c1);

            // branchless long-loop, unroll x2 accepted: 2 box loads (b128 only)
            // + 4 independent accumulation chains; areas recomputed in VALU
            float m0 = -1.f, m1 = -1.f;
            int a = sidx15;
            for (; a + 15 < accCount; a += 30) {
                float4 A0 = s_accB[a];
                float4 A1 = s_accB[a + 15];
                float Aa0 = area_of(A0);
                float Aa1 = area_of(A1);
                supp_acc(A0, Aa0, c0, a0, m0);
                supp_acc(A0, Aa0, c1, a1, m1);
                supp_acc(A1, Aa1, c0, a0, m0);
                supp_acc(A1, Aa1, c1, a1, m1);
            }
            if (a < accCount) {
                float4 A0 = s_accB[a];
                float Aa0 = area_of(A0);
                supp_acc(A0, Aa0, c0, a0, m0);
                supp_acc(A0, Aa0, c1, a1, m1);
            }
            bool s0 = (m0 >= 0.f), s1 = (m1 >= 0.f);
            bool rr = ((m0 < 0.f) && (m0 >= BAND)) || ((m1 < 0.f) && (m1 >= BAND));
            if (__builtin_expect(__any((int)rr), 0)) {
                for (int a2 = sidx15; a2 < accCount; a2 += 15) {
                    float4 A = s_accB[a2];
                    float Aa = area_of(A);
                    s0 |= supp_div(A, Aa, c0, a0);
                    s1 |= supp_div(A, Aa, c1, a1);
                }
            }
            if (s0 && c < C1) s_pre[p][c]      = 1u;   // same-value race, benign
            if (s1 && c < C2) s_pre[p][64 + c] = 1u;

            // intra half1: waves 2..9, 8 slices, branchless + deferred rerun
            if (wv >= 2 && wv <= 9 && c < C1) {
                int s8 = wv - 2;
                unsigned mlo = 0u, mhi = 0u;
                bool ur = false;
                for (int j = s8; j < c; j += 8) {        // j wave-uniform
                    float4 bj = s_cbox[p][j];
                    float  aj = area_of(bj);
                    bool sj, uj;
                    supp_bit(bj, aj, c0, a0, sj, uj);
                    ur |= uj;
                    unsigned bit = sj ? 1u : 0u;
                    if (j < 32) mlo |= bit << j; else mhi |= bit << (j - 32);
                }
                if (__builtin_expect(__any((int)ur), 0)) {
                    for (int j = s8; j < c; j += 8) {
                        float4 bj = s_cbox[p][j];
                        float  aj = area_of(bj);
                        unsigned bit = supp_div(bj, aj, c0, a0) ? 1u : 0u;
                        if (j < 32) mlo |= bit << j; else mhi |= bit << (j - 32);
                    }
                }
                if (mlo) atomicOr(&s_gmlo[p][c], mlo);
                if (mhi) atomicOr(&s_gmhi[p][c], mhi);
            }
        }
        __syncthreads();

        // ---------------- Region 2: resolve half1 || intra half2 ----------------
        if (tid < 64) {
            u64 mymask = ((u64)s_gmhi[p][tid] << 32) | (u64)s_gmlo[p][tid];
            bool alive = (tid < C1) && (s_pre[p][tid] == 0u);
            u64 accbits = 0ull, done = 0ull;
            int room = NSEL - accCount;
            int na = 0;
            while (na < room) {
                u64 am  = __ballot(alive);
                u64 rem = am & ~done;
                if (!rem) break;
                int l = __ffsll(rem) - 1;
                done = (2ull << l) - 1ull;
                accbits |= (1ull << l);
                ++na;
                if ((mymask >> l) & 1ull) alive = false;
            }
            if ((accbits >> tid) & 1ull) {
                int rank = __popcll(accbits & ((1ull << tid) - 1ull));
                s_accB[accCount + rank] = s_cbox[p][tid];
            }
            if (tid == 0) s_accCount = accCount + __popcll(accbits);
        } else if (wv >= 9 && c < C2) {
            // intra half2: waves 9..15, 7 slices (overlaps the serial resolve)
            int s7 = wv - 9;
            unsigned mlo = 0u, mhi = 0u;
            bool ur = false;
            for (int jj = s7; jj < c; jj += 7) {
                float4 bj = s_cbox[p][64 + jj];
                float  aj = area_of(bj);
                bool sj, uj;
                supp_bit(bj, aj, c1, a1, sj, uj);
                ur |= uj;
                unsigned bit = sj ? 1u : 0u;
                if (jj < 32) mlo |= bit << jj; else mhi |= bit << (jj - 32);
            }
            if (__builtin_expect(__any((int)ur), 0)) {
                for (int jj = s7; jj < c; jj += 7) {
                    float4 bj = s_cbox[p][64 + jj];
                    float  aj = area_of(bj);
                    unsigned bit = supp_div(bj, aj, c1, a1) ? 1u : 0u;
                    if (jj < 32) mlo |= bit << jj; else mhi |= bit << (jj - 32);
                }
            }
            if (mlo) atomicOr(&s_gmlo[p][64 + c], mlo);
            if (mhi) atomicOr(&s_gmhi[p][64 + c], mhi);
        }
        __syncthreads();
        int acc1 = s_accCount;

        // ---------------- Region 3: half2 vs half1's new accepts ----------------
        if (wv != 1) {
            float m1b = -1.f;
            for (int a3 = accCount + sidx15; a3 < acc1; a3 += 15) {
                float4 A = s_accB[a3];
                float Aa = area_of(A);
                supp_acc(A, Aa, c1, a1, m1b);
            }
            bool s1b = (m1b >= 0.f);
            bool rr  = (m1b < 0.f) && (m1b >= BAND);
            if (__builtin_expect(__any((int)rr), 0)) {
                for (int a3 = accCount + sidx15; a3 < acc1; a3 += 15) {
                    float4 A = s_accB[a3];
                    float Aa = area_of(A);
                    s1b |= supp_div(A, Aa, c1, a1);
                }
            }
            if (s1b && c < C2) s_pre[p][64 + c] = 1u;
        }
        __syncthreads();

        // ---------------- Region 4: resolve half2 ----------------
        if (tid < 64) {
            u64 mymask = ((u64)s_gmhi[p][64+tid] << 32) | (u64)s_gmlo[p][64+tid];
            bool alive = (tid < C2) && (s_pre[p][64+tid] == 0u);
            u64 accbits = 0ull, done = 0ull;
            int room = NSEL - acc1;
            int na = 0;
            while (na < room) {
                u64 am  = __ballot(alive);
                u64 rem = am & ~done;
                if (!rem) break;
                int l = __ffsll(rem) - 1;
                done = (2ull << l) - 1ull;
                accbits |= (1ull << l);
                ++na;
                if ((mymask >> l) & 1ull) alive = false;
            }
            if ((accbits >> tid) & 1ull) {
                int rank = __popcll(accbits & ((1ull << tid) - 1ull));
                s_accB[acc1 + rank] = s_cbox[p][64+tid];
            }
            if (tid == 0) s_accCount = acc1 + __popcll(accbits);
        }
        __syncthreads();
        accCount = s_accCount;
    }

    // ---- Phase C: select_rois ----
    if (tid < NGT) s_gt[tid] = gt4[tid];
    __syncthreads();

    if (tid < NSEL) {
        float4 bx;
        if (tid < accCount) {
            float4 r = s_accB[tid];
            bx = make_float4(clip01(r.x), clip01(r.y), clip01(r.z), clip01(r.w));
        } else bx = make_float4(0.f, 0.f, 0.f, 0.f);
        float aa = (bx.z - bx.x) * (bx.w - bx.y);
        float best = -1e38f; int bi = 0;
        for (int g = 0; g < NGT; ++g) {
            float4 gb = s_gt[g];
            float y1 = fmaxf(bx.x, gb.x);
            float x1 = fmaxf(bx.y, gb.y);
            float y2 = fminf(bx.z, gb.z);
            float x2 = fminf(bx.w, gb.w);
            float ih = fmaxf(y2 - y1, 0.0f);
            float iw = fmaxf(x2 - x1, 0.0f);
            float inter = ih * iw;
            float ab = (gb.z - gb.x) * (gb.w - gb.y);
            float iou = inter / (aa + ab - inter + 1e-7f);
            if (iou > best) { best = iou; bi = g; }   // first-occurrence argmax
        }
        s_merged[tid] = best;
        s_gtbest[tid] = bi;
    }
    __syncthreads();

    // stable top-64 via rank selection: rank = #{j: v_j > v_i || (v_j==v_i && j<i)}
    if (tid < NSEL) {
        float v = s_merged[tid];
        int rank = 0;
        for (int j = 0; j < NSEL; ++j) {
            float u = s_merged[j];
            rank += (u > v) || (u == v && j < tid);
        }
        if (rank < 64) s_selidx[rank] = tid;
    }
    __syncthreads();

    // ---- outputs ----
    float* outIdx = out + (size_t)NBATCH * 128 * 4;   // 8192 box floats first
    if (tid < 256) {
        int r = tid >> 2, cc = tid & 3;
        int i = s_selidx[r];
        float val = 0.0f;
        if (i < accCount) {
            const float* p = (const float*)&s_accB[i];
            val = clip01(p[cc]);
        }
        out[((size_t)b * 128 + r) * 4 + cc] = val;
    } else if (tid < 512) {
        int j = tid - 256;
        out[((size_t)b * 128 + 64) * 4 + j] = 0.0f;   // TOTAL_NEG zero boxes
    } else if (tid < 576) {
        int r = tid - 512;
        outIdx[b * 64 + r] = (float)s_gtbest[s_selidx[r]];
    }
}

extern "C" void kernel_launch(void* const* d_in, const int* in_sizes, int n_in,
                              void* d_out, int out_size, void* d_ws, size_t ws_size,
                              hipStream_t stream) {
    const float* deltas  = (const float*)d_in[0];
    const float* labels  = (const float*)d_in[1];
    const float* anchors = (const float*)d_in[2];
    const float* gt      = (const float*)d_in[3];
    float* out = (float*)d_out;
    roi_bbox_kernel<<<NBATCH, 1024, 0, stream>>>(deltas, labels, anchors, gt, out);
}